// Round 3
// baseline (24266.014 us; speedup 1.0000x reference)
//
#include <hip/hip_runtime.h>

// CascadedAttention: B=32, T=1024, D=1024, O=256. All I/O tensors are FLOAT32
// (per reference dtypes); internal staging E/IC in bf16 (ws), UoHp in d_out.
//
// Precompute:
//   E [b][o/8][t][8] = exp(2*(inputs[b,t,:]@Ua[:,o] + Ba2[t,o]))   (bf16, ws+0, 16MB)
//   IC[b][t][o]      = inputs[b,t,:]@Co[:,o]                        (bf16, ws+16MB)
//   out[b][t][o]     = inputs[b,t-1,:]@Uo[:,o] + Bo2+Bo3+Bo4        (f32, staged in d_out)
// Scan (1 block of 1024 thr per b, NO inter-block sync):
//   F[o]   = exp(2*(tanh(pred)@Wa + Ba1)[o])
//   tanh(UaH+WaS) = 1 - 2/(E*F+1)
//   score[t'] = sumVa - 2*sum_o Va[o]/(E[t',o]*F[o]+1) + Ba3[t'] -> softmax over t'
//   pred[o] = softmaxO(pred)@embWo + UoHp[t][o] + invL*sum_t' e[t']*IC[t'][o]

typedef unsigned int uint32;
typedef unsigned short u16;

__device__ __forceinline__ float b2f(u16 u) { return __uint_as_float(((uint32)u) << 16); }
__device__ __forceinline__ u16 f2b(float f) {
    uint32 u = __float_as_uint(f);
    uint32 r = u + 0x7fffu + ((u >> 16) & 1u);
    return (u16)(r >> 16);
}
__device__ __forceinline__ float lo_bf(uint32 d) { return __uint_as_float(d << 16); }
__device__ __forceinline__ float hi_bf(uint32 d) { return __uint_as_float(d & 0xffff0000u); }
__device__ __forceinline__ float tanh_fast(float x) {
    float e = __expf(x + x);
    return 1.0f - 2.0f * __builtin_amdgcn_rcpf(e + 1.0f);
}

#define OFF_E  ((size_t)0)
#define OFF_IC ((size_t)16777216)
#define WS_NEEDED ((size_t)33554432)

// ---------------- K1: fused precompute GEMM (f32 in, bf16/f32 out) ----------------
// grid (256 row-tiles, 6 col-tiles), 256 threads. Tile 128x128, K-chunk 32.
__global__ __launch_bounds__(256) void gemm_pre(
    const float* __restrict__ in, const float* __restrict__ Ua,
    const float* __restrict__ Uo, const float* __restrict__ Co,
    const float* __restrict__ Ba2, const float* __restrict__ Bo2,
    const float* __restrict__ Bo3, const float* __restrict__ Bo4,
    u16* __restrict__ E, float* __restrict__ outStage, u16* __restrict__ ic) {
    __shared__ __align__(16) float smA[32][132]; // A^T [k][row], padded
    __shared__ __align__(16) float smB[32][128];

    int tid = threadIdx.x;
    int rt = blockIdx.x, ct = blockIdx.y;
    int mat = ct >> 1;
    int o0 = (ct & 1) * 128;
    const float* W = (mat == 0) ? Ua : (mat == 1 ? Uo : Co);
    int r0 = rt * 128;
    int b = r0 >> 10, t0 = r0 & 1023;
    int tr = tid >> 4, tc = tid & 15;

    float acc[8][8];
#pragma unroll
    for (int i = 0; i < 8; i++)
#pragma unroll
        for (int j = 0; j < 8; j++) acc[i][j] = 0.f;

    for (int kc = 0; kc < 1024; kc += 32) {
#pragma unroll
        for (int l = 0; l < 4; l++) {
            int s = tid + l * 256;
            int i = s >> 3, c = s & 7;
            float4 v = *(const float4*)(in + (size_t)(r0 + i) * 1024 + kc + c * 4);
            smA[c * 4 + 0][i] = v.x;
            smA[c * 4 + 1][i] = v.y;
            smA[c * 4 + 2][i] = v.z;
            smA[c * 4 + 3][i] = v.w;
        }
#pragma unroll
        for (int l = 0; l < 4; l++) {
            int s = tid + l * 256;
            int dd = s >> 5, c = s & 31;
            *(float4*)&smB[dd][c * 4] = *(const float4*)(W + (size_t)(kc + dd) * 256 + o0 + c * 4);
        }
        __syncthreads();
#pragma unroll 4
        for (int j = 0; j < 32; j++) {
            float a0[8], b0[8];
            *(float4*)&a0[0] = *(const float4*)&smA[j][tr * 8];
            *(float4*)&a0[4] = *(const float4*)&smA[j][tr * 8 + 4];
            *(float4*)&b0[0] = *(const float4*)&smB[j][tc * 8];
            *(float4*)&b0[4] = *(const float4*)&smB[j][tc * 8 + 4];
#pragma unroll
            for (int rr = 0; rr < 8; rr++)
#pragma unroll
                for (int cc = 0; cc < 8; cc++) acc[rr][cc] = fmaf(a0[rr], b0[cc], acc[rr][cc]);
        }
        __syncthreads();
    }

    if (mat == 0) {
#pragma unroll
        for (int rr = 0; rr < 8; rr++) {
            int t = t0 + tr * 8 + rr;
#pragma unroll
            for (int cc = 0; cc < 8; cc++) {
                int o = o0 + tc * 8 + cc;
                float v = __expf(2.f * (acc[rr][cc] + Ba2[t * 256 + o]));
                E[((((size_t)b * 32 + (o >> 3)) << 10) + t) * 8 + (o & 7)] = f2b(v);
            }
        }
    } else if (mat == 1) {
#pragma unroll
        for (int rr = 0; rr < 8; rr++) {
            int t = t0 + tr * 8 + rr;
            int t1 = (t + 1) & 1023;
#pragma unroll
            for (int cc = 0; cc < 8; cc++) {
                int o = o0 + tc * 8 + cc;
                outStage[(((size_t)b << 10) + t1) * 256 + o] = acc[rr][cc] + Bo2[o] + Bo3[o] + Bo4[o];
            }
        }
    } else {
#pragma unroll
        for (int rr = 0; rr < 8; rr++) {
            int t = t0 + tr * 8 + rr;
#pragma unroll
            for (int cc = 0; cc < 8; cc++)
                ic[(((size_t)b << 10) + t) * 256 + o0 + tc * 8 + cc] = f2b(acc[rr][cc]);
        }
    }
}

// ---------------- K2: sequential scan, 1 block (1024 thr) per b ----------------
__global__ __launch_bounds__(1024) void seq1024(
    const float* __restrict__ Wa, const float* __restrict__ Va,
    const float* __restrict__ Ba1, const float* __restrict__ Ba3,
    const float* __restrict__ emb, const float* __restrict__ Wo,
    const u16* __restrict__ E, const u16* __restrict__ IC, float* __restrict__ out) {
    __shared__ float smPred[256], smQ[256], smF[256], smVa[256], smEmb[256], smBa1[256];
    __shared__ float smW[1024];
    __shared__ __align__(16) float smRed[4096];
    __shared__ float smMax16[16], smSum16[16], smMax4[4], smS1[4], smS2[4];

    int tid = threadIdx.x;
    int b = blockIdx.x;
    int lane = tid & 63, w = tid >> 6;
    int o = tid & 255, jc = tid >> 8;

    // one-time init
    if (tid < 256) {
        smPred[tid] = 0.f;
        smQ[tid] = 0.f;
        smVa[tid] = Va[tid];
        smBa1[tid] = Ba1[tid];
        float a = 0.f;
        for (int j = 0; j < 256; j++) a = fmaf(emb[tid * 256 + j], Wo[j], a);
        smEmb[tid] = a;
    }
    __syncthreads();
    if (tid < 256) {
        float v = smVa[tid];
#pragma unroll
        for (int off = 32; off; off >>= 1) v += __shfl_xor(v, off, 64);
        if (lane == 0) smMax4[w] = v;
    }
    __syncthreads();
    float sumVa = smMax4[0] + smMax4[1] + smMax4[2] + smMax4[3];
    __syncthreads(); // before smMax4 reuse

    // Wa chunk in registers (bf16-packed): thread (o, jc) holds Wa[jc*64 .. +63][o]
    uint32 WaP[32];
#pragma unroll 8
    for (int k = 0; k < 32; k++) {
        uint32 u0 = (uint32)f2b(Wa[(size_t)(jc * 64 + 2 * k) * 256 + o]);
        uint32 u1 = (uint32)f2b(Wa[(size_t)(jc * 64 + 2 * k + 1) * 256 + o]);
        WaP[k] = u0 | (u1 << 16);
    }

    const uint4* Eq = (const uint4*)(E + ((size_t)b * 32) * 8192); // [og*1024 + t']
    const u16* ICb = IC + ((size_t)b << 18);
    float* outb = out + ((size_t)b << 18);

    for (int t = 0; t < 1024; t++) {
        // ---- phase A: softmaxO max partial (tid<256) + WaS partials (all) ----
        float pv = 0.f;
        if (tid < 256) {
            pv = smPred[tid];
            float m = pv;
#pragma unroll
            for (int off = 32; off; off >>= 1) m = fmaxf(m, __shfl_xor(m, off, 64));
            if (lane == 0) smMax4[w] = m;
        }
        {
            float a = 0.f;
#pragma unroll 8
            for (int k = 0; k < 32; k++) {
                float2 q2 = *(const float2*)&smQ[jc * 64 + 2 * k];
                uint32 p = WaP[k];
                a = fmaf(lo_bf(p), q2.x, a);
                a = fmaf(hi_bf(p), q2.y, a);
            }
            smRed[jc * 256 + o] = a;
        }
        __syncthreads();
        // ---- phase B (tid<256): softmaxO sums; F = exp(2*WaS) ----
        if (tid < 256) {
            float M = fmaxf(fmaxf(smMax4[0], smMax4[1]), fmaxf(smMax4[2], smMax4[3]));
            float e = __expf(pv - M);
            float s1 = e, s2 = e * smEmb[tid];
#pragma unroll
            for (int off = 32; off; off >>= 1) {
                s1 += __shfl_xor(s1, off, 64);
                s2 += __shfl_xor(s2, off, 64);
            }
            if (lane == 0) { smS1[w] = s1; smS2[w] = s2; }
            float was = smBa1[tid] + smRed[tid] + smRed[256 + tid] + smRed[512 + tid] + smRed[768 + tid];
            smF[tid] = __expf(2.f * was);
        }
        __syncthreads();
        // ---- phase C: score for t' = tid ----
        float acc = 0.f;
        {
            const uint4* ept = Eq + tid;
#pragma unroll 4
            for (int og = 0; og < 32; og++) {
                uint4 ev = ept[og << 10];
                float4 fA = *(const float4*)&smF[og * 8];
                float4 fB = *(const float4*)&smF[og * 8 + 4];
                float4 vA = *(const float4*)&smVa[og * 8];
                float4 vB = *(const float4*)&smVa[og * 8 + 4];
                acc = fmaf(vA.x, __builtin_amdgcn_rcpf(fmaf(lo_bf(ev.x), fA.x, 1.f)), acc);
                acc = fmaf(vA.y, __builtin_amdgcn_rcpf(fmaf(hi_bf(ev.x), fA.y, 1.f)), acc);
                acc = fmaf(vA.z, __builtin_amdgcn_rcpf(fmaf(lo_bf(ev.y), fA.z, 1.f)), acc);
                acc = fmaf(vA.w, __builtin_amdgcn_rcpf(fmaf(hi_bf(ev.y), fA.w, 1.f)), acc);
                acc = fmaf(vB.x, __builtin_amdgcn_rcpf(fmaf(lo_bf(ev.z), fB.x, 1.f)), acc);
                acc = fmaf(vB.y, __builtin_amdgcn_rcpf(fmaf(hi_bf(ev.z), fB.y, 1.f)), acc);
                acc = fmaf(vB.z, __builtin_amdgcn_rcpf(fmaf(lo_bf(ev.w), fB.z, 1.f)), acc);
                acc = fmaf(vB.w, __builtin_amdgcn_rcpf(fmaf(hi_bf(ev.w), fB.w, 1.f)), acc);
            }
        }
        float score = sumVa - 2.f * acc + Ba3[tid];
        float m2 = score;
#pragma unroll
        for (int off = 32; off; off >>= 1) m2 = fmaxf(m2, __shfl_xor(m2, off, 64));
        if (lane == 0) smMax16[w] = m2;
        __syncthreads();
        float M2 = smMax16[0];
#pragma unroll
        for (int i = 1; i < 16; i++) M2 = fmaxf(M2, smMax16[i]);
        float ee = __expf(score - M2);
        smW[tid] = ee;
        float ls = ee;
#pragma unroll
        for (int off = 32; off; off >>= 1) ls += __shfl_xor(ls, off, 64);
        if (lane == 0) smSum16[w] = ls;
        __syncthreads();
        // ---- phase D: output partials: 16 t'-chunks x 64 t', 4 o's/thread ----
        {
            int tc = tid >> 6, o4 = (tid & 63) << 2;
            const u16* icp = ICb + ((size_t)(tc << 6) << 8) + o4;
            float4 a4 = {0.f, 0.f, 0.f, 0.f};
#pragma unroll 4
            for (int i = 0; i < 64; i++) {
                float wv = smW[(tc << 6) + i];
                uint2 iv = *(const uint2*)(icp + ((size_t)i << 8));
                a4.x = fmaf(wv, lo_bf(iv.x), a4.x);
                a4.y = fmaf(wv, hi_bf(iv.x), a4.y);
                a4.z = fmaf(wv, lo_bf(iv.y), a4.z);
                a4.w = fmaf(wv, hi_bf(iv.y), a4.w);
            }
            *(float4*)&smRed[tc * 256 + o4] = a4;
        }
        __syncthreads();
        // ---- phase E (tid<256): final combine, write out, next-step state ----
        if (tid < 256) {
            float s = 0.f;
#pragma unroll
            for (int c = 0; c < 16; c++) s += smRed[c * 256 + tid];
            float L = 0.f;
#pragma unroll
            for (int i = 0; i < 16; i++) L += smSum16[i];
            float invL = __builtin_amdgcn_rcpf(L);
            float p_val = (smS2[0] + smS2[1] + smS2[2] + smS2[3]) *
                          __builtin_amdgcn_rcpf(smS1[0] + smS1[1] + smS1[2] + smS1[3]);
            float uoh = outb[((size_t)t << 8) + tid];   // staged UoHp (f32)
            float pr = p_val + uoh + invL * s;
            outb[((size_t)t << 8) + tid] = pr;
            smPred[tid] = pr;
            smQ[tid] = tanh_fast(pr);
        }
        __syncthreads();
    }
}

// ---------------- fallback (ws too small): diagnostic zero-fill ----------------
__global__ void zero_k(uint32* out, int n) {
    int i = blockIdx.x * 1024 + threadIdx.x;
    if (i < n) out[i] = 0;
}

extern "C" void kernel_launch(void* const* d_in, const int* in_sizes, int n_in,
                              void* d_out, int out_size, void* d_ws, size_t ws_size,
                              hipStream_t stream) {
    const float* in = (const float*)d_in[0];
    const float* Wa = (const float*)d_in[1];
    const float* Ua = (const float*)d_in[2];
    const float* Va = (const float*)d_in[3];
    const float* Ba1 = (const float*)d_in[4];
    const float* Ba2 = (const float*)d_in[5];
    const float* Ba3 = (const float*)d_in[6];
    // d_in[7] = Wo used below; order per setup_inputs
    const float* Wo = (const float*)d_in[7];
    const float* Uo = (const float*)d_in[8];
    const float* Co = (const float*)d_in[9];
    const float* Bo2 = (const float*)d_in[10];
    const float* Bo3 = (const float*)d_in[11];
    const float* Bo4 = (const float*)d_in[12];
    const float* emb = (const float*)d_in[13];
    float* out = (float*)d_out;
    char* ws = (char*)d_ws;

    if (ws_size < WS_NEEDED) {
        zero_k<<<(out_size + 1023) / 1024, 1024, 0, stream>>>((uint32*)out, out_size);
        return;
    }

    u16* E = (u16*)(ws + OFF_E);
    u16* icp = (u16*)(ws + OFF_IC);

    gemm_pre<<<dim3(256, 6), 256, 0, stream>>>(in, Ua, Uo, Co, Ba2, Bo2, Bo3, Bo4, E, out, icp);
    seq1024<<<32, 1024, 0, stream>>>(Wa, Va, Ba1, Ba3, emb, Wo, E, icp, out);
}